// Round 9
// baseline (100.175 us; speedup 1.0000x reference)
//
#include <hip/hip_runtime.h>

#define PATCH_N 64
#define CH      4
#define PADDED  192
#define BATCH   512
#define THREADS 512                       // 8 waves
#define PROWS   66                        // guard row 0, data rows 1..64, guard 65
#define PCOLS   76                        // guard cols + shifted 65-col data window
#define PLANE_F (PROWS * PCOLS)           // 5016 floats per channel plane
#define LDS_F   (CH * PLANE_F)            // 20064 floats = 80,256 B

__device__ __forceinline__ int   rfl_i(int x)   { return __builtin_amdgcn_readfirstlane(x); }
__device__ __forceinline__ float rfl_f(float x) { return __int_as_float(__builtin_amdgcn_readfirstlane(__float_as_int(x))); }

// H-plane gather (v8 algorithm) at 512 threads/block so TWO blocks co-reside
// per CU (1024 thr, 160.5 KB LDS): exactly one dispatch round, and the two
// blocks' independent barriers let one block's patch reads overlap the
// other's output writes. Patch prefetch is issued BEFORE the LDS zero phase
// to hide global-load latency behind it.
//   H_c(r,j) = wx0*P(r,j) + wx1*P(r,j+1), j in [-1,63], stored
//   alignment-shifted so each output float4 reads its taps as ONE aligned
//   ds_read_b128; guard rows/cols are zero -> no masks in the inner loop.
//   out(y,x) = sum_c wy0_c*H_c(y-sy_c,x) + wy1_c*H_c(y-sy_c+1,x)
__global__ __launch_bounds__(THREADS, 4)
void reassemble_h9(const float* __restrict__ patches,
                   const float* __restrict__ positions,
                   float* __restrict__ out)
{
    __shared__ float4 lds4[LDS_F / 4];
    float* __restrict__ lds = reinterpret_cast<float*>(lds4);

    const int b    = blockIdx.x;
    const int tid  = threadIdx.x;
    const int lane = tid & 63;
    const int wid  = rfl_i(tid >> 6);     // 0..7

    // ---- prefetch patch rows FIRST (latency hides behind zero phase) ----
    const float4* __restrict__ p4 =
        reinterpret_cast<const float4*>(patches) + (size_t)b * (PATCH_N * PATCH_N);
    float4 vals[8];
#pragma unroll
    for (int pass = 0; pass < 8; ++pass) {
        const int r = pass * 8 + wid;                 // wave-uniform row
        vals[pass] = p4[r * PATCH_N + lane];          // coalesced 1 KB/wave
    }

    // ---- per-channel uniform constants (SGPR) ----
    const float* pos = positions + (size_t)b * 8;     // (1,2,C): dx[c] then dy[c]
    int   syc[CH], ac[CH], padc[CH];
    float wx0c[CH], wx1c[CH], wy0c[CH], wy1c[CH];
#pragma unroll
    for (int c = 0; c < CH; ++c) {
        const float tx  = 64.f + rfl_f(pos[c]);
        const float sxf = ceilf(tx);
        const int   sx  = rfl_i((int)sxf);            // in [2,127]
        wx1c[c] = rfl_f(sxf - tx);
        wx0c[c] = 1.f - wx1c[c];
        const float ty  = 64.f + rfl_f(pos[CH + c]);
        const float syf = ceilf(ty);
        syc[c]  = rfl_i((int)syf);
        wy1c[c] = rfl_f(syf - ty);
        wy0c[c] = 1.f - wy1c[c];
        ac[c]   = (sx - 1) >> 2;          // alignment block of left data col
        padc[c] = (sx - 1) & 3;           // column shift within 16B
    }

    // ---- zero all planes (guards stay zero; data overwritten below) ----
#pragma unroll
    for (int j = 0; j < (LDS_F / 4 + THREADS - 1) / THREADS; ++j) {   // 10 iters
        const int idx = j * THREADS + tid;
        if (idx < LDS_F / 4) lds4[idx] = make_float4(0.f, 0.f, 0.f, 0.f);
    }
    __syncthreads();

    // ---- stage + horizontal pre-blend: patch row r, lane = col ----
    const bool last = (lane == 63);
#pragma unroll
    for (int pass = 0; pass < 8; ++pass) {
        const int r = pass * 8 + wid;
        const float4 v = vals[pass];
#pragma unroll
        for (int c = 0; c < CH; ++c) {
            const float val = (c == 0) ? v.x : (c == 1) ? v.y : (c == 2) ? v.z : v.w;
            float vr = __shfl_down(val, 1);           // P(r, lane+1)
            vr = last ? 0.f : vr;                     // P(r,64) = 0
            const float h = fmaf(wx1c[c], vr, wx0c[c] * val);   // H(r, lane)
            float* pl = lds + c * PLANE_F + (r + 1) * PCOLS;
            pl[lane + padc[c] + 5] = h;               // data col for j=lane
            if (lane == 0) pl[padc[c] + 4] = wx1c[c] * val;     // H(r,-1)
        }
    }
    __syncthreads();

    // ---- compute: each thread one output float4 per iter ----
    float4* __restrict__ o4 =
        reinterpret_cast<float4*>(out) + (size_t)b * (PADDED * PADDED / 4);

#pragma unroll
    for (int it = 0; it < (PADDED * PADDED / 4) / THREADS; ++it) {   // 18 iters
        const int idx = it * THREADS + tid;
        const int y   = idx / 48;                     // row (monotone in lane)
        const int xg  = idx - y * 48;                 // float4 group in row
        const int y0  = rfl_i(y);                     // wave min-y
        const int yp1 = y + 1;
        float a0 = 0.f, a1 = 0.f, a2 = 0.f, a3 = 0.f;

#pragma unroll
        for (int c = 0; c < CH; ++c) {
            // wave y-range [y0, y0+2] vs channel window [sy-1, sy+63]: scalar skip
            if (y0 + 2 < syc[c] - 1 || y0 > syc[c] + 63) continue;

            const int t    = yp1 - syc[c];            // plane row of top tap
            const int row0 = min(max(t, 0), 65);      // clamp -> guard rows
            const int row1 = min(max(t, -1), 64) + 1; // independent clamp
            const int q4   = min(max(xg - ac[c] + 1, 0), 18);  // aligned col grp
            const int base = c * (PLANE_F / 4) + q4;  // float4 index
            const float4 W0 = lds4[base + row0 * (PCOLS / 4)]; // ds_read_b128
            const float4 W1 = lds4[base + row1 * (PCOLS / 4)];

            const float wy0 = wy0c[c], wy1 = wy1c[c];
            a0 = fmaf(wy0, W0.x, a0); a0 = fmaf(wy1, W1.x, a0);
            a1 = fmaf(wy0, W0.y, a1); a1 = fmaf(wy1, W1.y, a1);
            a2 = fmaf(wy0, W0.z, a2); a2 = fmaf(wy1, W1.z, a2);
            a3 = fmaf(wy0, W0.w, a3); a3 = fmaf(wy1, W1.w, a3);
        }

        o4[idx] = make_float4(a0, a1, a2, a3);        // 1 KB contiguous per wave
    }
}

extern "C" void kernel_launch(void* const* d_in, const int* in_sizes, int n_in,
                              void* d_out, int out_size, void* d_ws, size_t ws_size,
                              hipStream_t stream) {
    const float* patches   = (const float*)d_in[0];
    const float* positions = (const float*)d_in[1];
    float* out = (float*)d_out;

    reassemble_h9<<<dim3(BATCH), THREADS, 0, stream>>>(patches, positions, out);
}